// Round 6
// baseline (879.054 us; speedup 1.0000x reference)
//
#include <hip/hip_runtime.h>

// ---------------- problem constants ----------------
constexpr int Nn   = 100000;   // nodes
constexpr int Ee   = 1600000;  // edges
constexpr int D    = 128;      // hidden = input dim
constexpr int DOUT = 40;       // classifier out
constexpr int DCAT = 384;      // 3*D concat width
constexpr int CPAD = 48;       // DOUT padded to 3x16 MFMA col tiles
constexpr int WS   = 392;      // Wct row stride (halfs)

// feature-blocked tmp: 8 blocks x 16 features (32 B rows, 3.2 MB/block -> fits XCD L2)
constexpr int NFB    = 8;
constexpr int BLKSTR = (Nn + 1) * 16;  // f16 elems per block (+1 sentinel zero row)

// binned-sort parameters
constexpr int BINSH  = 8;                          // 256 nodes per bin
constexpr int BINSZ  = 1 << BINSH;
constexpr int BINS   = (Nn + BINSZ - 1) / BINSZ;   // 391
constexpr int CHUNK  = 8192;                       // edges per scatter block
constexpr int NCHUNK = (Ee + CHUNK - 1) / CHUNK;   // 196
constexpr int SEGCAP = 5376;                       // max edges/bin (mean 4092, +20 sigma)
constexpr int PADCAP = SEGCAP + 7 * BINSZ;         // 7168: per-bin padded arena stride

typedef _Float16 f16;
typedef _Float16 f16x2 __attribute__((ext_vector_type(2)));
typedef _Float16 f16x8 __attribute__((ext_vector_type(8)));
typedef float    f32x4 __attribute__((ext_vector_type(4)));

// ---------------- edge dtype detect ----------------
__global__ void detect_layout(const int* __restrict__ ei, int* __restrict__ flag) {
    if (threadIdx.x == 0 && blockIdx.x == 0) {
        unsigned orv = 0;
        for (int j = 0; j < 256; ++j) orv |= (unsigned)ei[2 * j + 1];
        *flag = (orv == 0u) ? 1 : 0;  // 1 => int64 layout
    }
}

__device__ inline void load_edge(const int* __restrict__ ei, int f, int e, int& s, int& d) {
    if (f) {  // int64: read 8B, use low word
        s = ((const int2*)ei)[e].x;
        d = ((const int2*)ei)[Ee + e].x;
    } else {
        s = ei[e];
        d = ei[Ee + e];
    }
}

// inclusive Hillis-Steele scan of n2 (<=512) ints with 256 threads, double-buffered.
__device__ inline int* scan_incl(int* pa, int* pb, int n2, int tid) {
    for (int off = 1; off < n2; off <<= 1) {
        for (int i = tid; i < n2; i += 256) pb[i] = pa[i] + ((i >= off) ? pa[i - off] : 0);
        __syncthreads();
        int* t = pa; pa = pb; pb = t;
    }
    return pa;
}

// ---------------- P1: per-bin edge histogram ----------------
__global__ __launch_bounds__(256) void bin_hist(const int* __restrict__ ei,
                                                const int* __restrict__ flag,
                                                int* __restrict__ binCnt) {
    __shared__ int h[BINS];
    for (int i = threadIdx.x; i < BINS; i += 256) h[i] = 0;
    __syncthreads();
    int f = *flag;
    for (int e = blockIdx.x * 256 + threadIdx.x; e < Ee; e += gridDim.x * 256) {
        int s, d;
        load_edge(ei, f, e, s, d);
        if ((unsigned)s < (unsigned)Nn && (unsigned)d < (unsigned)Nn)
            atomicAdd(&h[d >> BINSH], 1);
    }
    __syncthreads();
    for (int i = threadIdx.x; i < BINS; i += 256)
        if (h[i]) atomicAdd(&binCnt[i], h[i]);
}

// ---------------- P2: scan bins -> arena offsets + cursors ----------------
__global__ __launch_bounds__(512) void bin_scan(const int* __restrict__ binCnt,
                                                int* __restrict__ binOff,
                                                int* __restrict__ binCursor) {
    __shared__ int a[512];
    int t = threadIdx.x;
    int v = (t < BINS) ? binCnt[t] : 0;
    a[t] = v;
    __syncthreads();
    for (int off = 1; off < 512; off <<= 1) {
        int x = a[t] + ((t >= off) ? a[t - off] : 0);
        __syncthreads();
        a[t] = x;
        __syncthreads();
    }
    if (t < BINS) { binOff[t] = a[t] - v; binCursor[t] = a[t] - v; }
    if (t == 0) binOff[BINS] = a[BINS - 1];
}

// ---------------- P3: binning scatter (coalesced run writes) ----------------
__global__ __launch_bounds__(256) void bin_scatter(const int* __restrict__ ei,
                                                   const int* __restrict__ flag,
                                                   int* __restrict__ binCursor,
                                                   unsigned* __restrict__ arena) {
    __shared__ unsigned srec[CHUNK];                       // 32 KB
    __shared__ int bcnt[BINS], bpfx[BINS], bfill[BINS], gbase[BINS];
    __shared__ int pA[512], pB[512];
    const int tid = threadIdx.x;
    const int e0 = blockIdx.x * CHUNK;
    const int n = min(CHUNK, Ee - e0);
    const int f = *flag;

    for (int i = tid; i < BINS; i += 256) { bcnt[i] = 0; bfill[i] = 0; }
    __syncthreads();
    for (int i = tid; i < n; i += 256) {
        int s, d;
        load_edge(ei, f, e0 + i, s, d);
        if ((unsigned)s < (unsigned)Nn && (unsigned)d < (unsigned)Nn)
            atomicAdd(&bcnt[d >> BINSH], 1);
    }
    __syncthreads();
    for (int i = tid; i < 512; i += 256) pA[i] = (i < BINS) ? bcnt[i] : 0;
    __syncthreads();
    int* incl = scan_incl(pA, pB, 512, tid);
    for (int i = tid; i < BINS; i += 256) {
        bpfx[i] = incl[i] - bcnt[i];
        gbase[i] = bcnt[i] ? atomicAdd(&binCursor[i], bcnt[i]) : 0;
    }
    __syncthreads();
    for (int i = tid; i < n; i += 256) {
        int s, d;
        load_edge(ei, f, e0 + i, s, d);
        if ((unsigned)s < (unsigned)Nn && (unsigned)d < (unsigned)Nn) {
            int bin = d >> BINSH;
            int lp = atomicAdd(&bfill[bin], 1);
            srec[bpfx[bin] + lp] = ((unsigned)(d & (BINSZ - 1)) << 17) | (unsigned)s;
        }
    }
    __syncthreads();
    const int wid = tid >> 6, lane = tid & 63;
    for (int bin = wid; bin < BINS; bin += 4) {
        int cnt = bcnt[bin], off = bpfx[bin], gb = gbase[bin];
        for (int j = lane; j < cnt; j += 64) arena[gb + j] = srec[off + j];
    }
}

// ---------------- P4: per-bin finalize -> PADDED CSR (+deg, dinv) ----------------
// Each node's list padded to a multiple of 8 with sentinel Nn (the zero row).
__global__ __launch_bounds__(256) void bin_finalize(const int* __restrict__ binOff,
                                                    const unsigned* __restrict__ arena,
                                                    int* __restrict__ rowPtrPad,
                                                    int* __restrict__ deg,
                                                    float* __restrict__ dinv,
                                                    int* __restrict__ sortedSrc) {
    __shared__ unsigned seg[SEGCAP];   // 21 KB
    __shared__ int ssrc[PADCAP];       // 28.7 KB
    __shared__ int cnt[BINSZ], fill[BINSZ], pA[BINSZ], pB[BINSZ];
    const int tid = threadIdx.x;
    const int b = blockIdx.x;
    const int base = binOff[b];
    int len = binOff[b + 1] - base;
    if (len > SEGCAP) len = SEGCAP;

    for (int i = tid; i < len; i += 256) seg[i] = arena[base + i];
    for (int i = tid; i < BINSZ; i += 256) { cnt[i] = 0; fill[i] = 0; }
    __syncthreads();
    for (int i = tid; i < len; i += 256) atomicAdd(&cnt[seg[i] >> 17], 1);
    __syncthreads();
    for (int i = tid; i < BINSZ; i += 256) pA[i] = (cnt[i] + 7) & ~7;  // padded counts
    __syncthreads();
    int* incl = scan_incl(pA, pB, BINSZ, tid);

    const int node0 = b * BINSZ;
    const int padLen = incl[BINSZ - 1];
    for (int t = tid; t < BINSZ; t += 256) {
        int node = node0 + t;
        if (node < Nn) {
            int pc = (cnt[t] + 7) & ~7;
            rowPtrPad[node] = b * PADCAP + incl[t] - pc;
            deg[node] = cnt[t];
            dinv[node] = rsqrtf((float)(cnt[t] + 1));  // +1 self loop
        }
    }
    for (int i = tid; i < padLen; i += 256) ssrc[i] = Nn;  // sentinel -> zero row
    __syncthreads();
    for (int i = tid; i < len; i += 256) {
        unsigned r = seg[i];
        int dl = r >> 17, s = (int)(r & 0x1FFFFu);
        int pc = (cnt[dl] + 7) & ~7;
        int p = atomicAdd(&fill[dl], 1);
        ssrc[incl[dl] - pc + p] = s;
    }
    __syncthreads();
    for (int i = tid; i < padLen; i += 256) sortedSrc[(size_t)b * PADCAP + i] = ssrc[i];
}

// ---------------- W transpose + fp16 convert: Wt[c][k] = W[k][c] (conv weights) ----------------
__global__ __launch_bounds__(256) void transpose_w(const float* __restrict__ W0,
                                                   const float* __restrict__ W1,
                                                   const float* __restrict__ W2,
                                                   f16* __restrict__ T) {
    const float* W = (blockIdx.x == 0) ? W0 : ((blockIdx.x == 1) ? W1 : W2);
    f16* Wt = T + (size_t)blockIdx.x * D * D;
    for (int i = threadIdx.x; i < D * D; i += 256) {
        int k = i >> 7, c = i & 127;
        Wt[c * D + k] = (f16)W[i];
    }
}

// ---------------- W_cls transpose+pad + tmpb sentinel zeroing ----------------
__global__ __launch_bounds__(256) void prep_wcls(const float* __restrict__ Wc,
                                                 f16* __restrict__ Wct,
                                                 f16* __restrict__ tmpb) {
    if (threadIdx.x < NFB * 16) {  // zero the 8 sentinel rows (row Nn of each block)
        int fb = threadIdx.x >> 4, j = threadIdx.x & 15;
        tmpb[(size_t)fb * BLKSTR + (size_t)Nn * 16 + j] = (f16)0.0f;
    }
    for (int i = threadIdx.x; i < CPAD * WS; i += 256) {
        int c = i / WS, k = i - c * WS;
        f16 v = (f16)0.0f;
        if (c < DOUT && k < DCAT) v = (f16)Wc[k * DOUT + c];
        Wct[i] = v;
    }
}

// ---------------- MFMA GEMM ----------------
// C = act(A[M,128] @ Wt^T (+bias)) * scale.  BLOCKED=0: row-major C (stride sC).
// BLOCKED=1: feature-blocked C: C[fb][row][16] with fb = col/16 (for aggregate_blk).
template <int AFP32, int BLOCKED>
__global__ __launch_bounds__(256) void gemm_mfma(const void* __restrict__ Ain, int sA,
                                                 const f16* __restrict__ Wt,
                                                 const float* __restrict__ bias,
                                                 const float* __restrict__ scale,
                                                 f16* __restrict__ C, int sC,
                                                 int M, int doRelu) {
    __shared__ f16 Bsw[128 * 128];  // 32 KB
    const int tid = threadIdx.x;
    const int r0 = blockIdx.x * 128;

    {   // stage B
        int row = tid >> 1, half = (tid & 1) * 128;
#pragma unroll
        for (int i = 0; i < 8; ++i) {
            int bir = half + i * 16;
            uint4 v = *(const uint4*)((const char*)Wt + (size_t)row * 256 + bir);
            *(uint4*)((char*)Bsw + row * 256 + (bir ^ ((row & 7) << 4))) = v;
        }
    }
    __syncthreads();

    const int lane = tid & 63;
    const int w    = tid >> 6;
    const int wr   = w * 32;

    f32x4 acc[2][8];
#pragma unroll
    for (int mf = 0; mf < 2; ++mf)
#pragma unroll
        for (int nf = 0; nf < 8; ++nf) acc[mf][nf] = (f32x4){0, 0, 0, 0};

#pragma unroll
    for (int kk = 0; kk < 4; ++kk) {
        const int ke = kk * 32 + (lane >> 4) * 8;  // k element offset for this lane
        f16x8 a[2], b[8];
#pragma unroll
        for (int mf = 0; mf < 2; ++mf) {
            int row = r0 + wr + mf * 16 + (lane & 15);
            int rc = (row < M) ? row : (M - 1);  // clamp; OOB rows never stored
            if (AFP32) {
                const float* p = (const float*)Ain + (size_t)rc * sA + ke;
                float4 f0 = *(const float4*)p;
                float4 f1 = *(const float4*)(p + 4);
                f16x8 h;
                h[0] = (f16)f0.x; h[1] = (f16)f0.y; h[2] = (f16)f0.z; h[3] = (f16)f0.w;
                h[4] = (f16)f1.x; h[5] = (f16)f1.y; h[6] = (f16)f1.z; h[7] = (f16)f1.w;
                a[mf] = h;
            } else {
                a[mf] = *(const f16x8*)((const f16*)Ain + (size_t)rc * sA + ke);
            }
        }
#pragma unroll
        for (int nf = 0; nf < 8; ++nf) {
            int col = nf * 16 + (lane & 15);
            int bir = kk * 64 + (lane >> 4) * 16;
            b[nf] = *(const f16x8*)((const char*)Bsw + col * 256 + (bir ^ ((col & 7) << 4)));
        }
#pragma unroll
        for (int mf = 0; mf < 2; ++mf)
#pragma unroll
            for (int nf = 0; nf < 8; ++nf)
                acc[mf][nf] = __builtin_amdgcn_mfma_f32_16x16x32_f16(a[mf], b[nf], acc[mf][nf], 0, 0, 0);
    }

    float bv[8];
#pragma unroll
    for (int nf = 0; nf < 8; ++nf) bv[nf] = bias ? bias[nf * 16 + (lane & 15)] : 0.0f;
#pragma unroll
    for (int mf = 0; mf < 2; ++mf) {
#pragma unroll
        for (int i = 0; i < 4; ++i) {
            int row = r0 + wr + mf * 16 + (lane >> 4) * 4 + i;
            if (row < M) {
                float sc = scale ? scale[row] : 1.0f;
#pragma unroll
                for (int nf = 0; nf < 8; ++nf) {
                    float v = acc[mf][nf][i] + bv[nf];
                    if (doRelu && v < 0.0f) v = 0.0f;
                    if (BLOCKED)
                        C[(size_t)nf * BLKSTR + (size_t)row * 16 + (lane & 15)] = (f16)(v * sc);
                    else
                        C[(size_t)row * sC + nf * 16 + (lane & 15)] = (f16)(v * sc);
                }
            }
        }
    }
}

// ---------------- feature-blocked aggregation with XCD affinity ----------------
// Block handles (4 nodes) x (one 16-feature block fb = blockIdx&7). Consecutive
// blockIdx round-robin across the 8 XCDs, so each XCD only gathers from its own
// 3.2 MB tmpb block -> L2-resident. Lane = edge-slot (lane&7) x feature-pair (lane>>3).
__global__ __launch_bounds__(256) void aggregate_blk(const f16* __restrict__ tmpb,
                                                     const int* __restrict__ rowPtrPad,
                                                     const int* __restrict__ deg,
                                                     const int* __restrict__ sortedSrc,
                                                     const float* __restrict__ dinv,
                                                     const float* __restrict__ bias,
                                                     f16* __restrict__ hcat, int partOff) {
    const int fb   = blockIdx.x & 7;
    const int node = (blockIdx.x >> 3) * 4 + (threadIdx.x >> 6);  // Nn % 4 == 0
    const int lane = threadIdx.x & 63;
    const int r = lane & 7;   // edge slot
    const int f = lane >> 3;  // feature pair (0..7)
    const f16x2* tb = (const f16x2*)(tmpb + (size_t)fb * BLKSTR);

    const int base = rowPtrPad[node];
    const int pc = (deg[node] + 7) & ~7;
    const float di = dinv[node];

    f16x2 sv = tb[(size_t)node * 8 + f];  // self (already *dinv[node]); count once (r==0)
    float ax = (r == 0) ? (float)sv[0] : 0.0f;
    float ay = (r == 0) ? (float)sv[1] : 0.0f;

    for (int e = 0; e < pc; e += 16) {  // unroll-2: two gathers in flight
        int s0 = __builtin_nontemporal_load(sortedSrc + base + e + r);
        f16x2 g0 = tb[(size_t)s0 * 8 + f];
        if (e + 8 < pc) {  // wave-uniform
            int s1 = __builtin_nontemporal_load(sortedSrc + base + e + 8 + r);
            f16x2 g1 = tb[(size_t)s1 * 8 + f];
            ax += (float)g0[0] + (float)g1[0];
            ay += (float)g0[1] + (float)g1[1];
        } else {
            ax += (float)g0[0];
            ay += (float)g0[1];
        }
    }
#pragma unroll
    for (int m = 1; m <= 4; m <<= 1) {  // reduce over the 8 edge-slot lanes
        ax += __shfl_xor(ax, m, 64);
        ay += __shfl_xor(ay, m, 64);
    }
    if (r == 0) {
        float2 bb = *(const float2*)(bias + fb * 16 + f * 2);
        float ox = di * ax + bb.x;
        float oy = di * ay + bb.y;
        if (ox < 0.0f) ox = 0.0f;
        if (oy < 0.0f) oy = 0.0f;
        f16x2 o;
        o[0] = (f16)ox;
        o[1] = (f16)oy;
        __builtin_nontemporal_store(o, (f16x2*)(hcat + (size_t)node * DCAT + partOff + fb * 16 + f * 2));
    }
}

// ---------------- MFMA classifier: out[N,40] = hcat[N,384] @ Wct^T + b ----------------
__global__ __launch_bounds__(256) void cls_mfma(const f16* __restrict__ hcat,
                                                const f16* __restrict__ Wct,
                                                const float* __restrict__ bc,
                                                float* __restrict__ out) {
    __shared__ f16 Bs[CPAD * WS];  // 37.6 KB
    const int tid = threadIdx.x;
    for (int i = tid; i < CPAD * WS / 8; i += 256)
        ((uint4*)Bs)[i] = ((const uint4*)Wct)[i];
    __syncthreads();

    const int lane = tid & 63;
    const int w    = tid >> 6;
    const int r0   = blockIdx.x * 128 + w * 32;

    f32x4 acc[2][3];
#pragma unroll
    for (int mf = 0; mf < 2; ++mf)
#pragma unroll
        for (int nf = 0; nf < 3; ++nf) acc[mf][nf] = (f32x4){0, 0, 0, 0};

#pragma unroll 3
    for (int kk = 0; kk < 12; ++kk) {
        const int ke = kk * 32 + (lane >> 4) * 8;
        f16x8 a[2], b[3];
#pragma unroll
        for (int mf = 0; mf < 2; ++mf) {
            int row = r0 + mf * 16 + (lane & 15);
            int rc = (row < Nn) ? row : (Nn - 1);
            a[mf] = *(const f16x8*)(hcat + (size_t)rc * DCAT + ke);
        }
#pragma unroll
        for (int nf = 0; nf < 3; ++nf) {
            int col = nf * 16 + (lane & 15);
            b[nf] = *(const f16x8*)(Bs + col * WS + ke);
        }
#pragma unroll
        for (int mf = 0; mf < 2; ++mf)
#pragma unroll
            for (int nf = 0; nf < 3; ++nf)
                acc[mf][nf] = __builtin_amdgcn_mfma_f32_16x16x32_f16(a[mf], b[nf], acc[mf][nf], 0, 0, 0);
    }

    float bv[3];
#pragma unroll
    for (int nf = 0; nf < 3; ++nf) {
        int col = nf * 16 + (lane & 15);
        bv[nf] = (col < DOUT) ? bc[col] : 0.0f;
    }
#pragma unroll
    for (int mf = 0; mf < 2; ++mf) {
#pragma unroll
        for (int i = 0; i < 4; ++i) {
            int row = r0 + mf * 16 + (lane >> 4) * 4 + i;
            if (row < Nn) {
#pragma unroll
                for (int nf = 0; nf < 3; ++nf) {
                    int col = nf * 16 + (lane & 15);
                    if (col < DOUT) out[(size_t)row * DOUT + col] = acc[mf][nf][i] + bv[nf];
                }
            }
        }
    }
}

// ---------------- launch ----------------
extern "C" void kernel_launch(void* const* d_in, const int* in_sizes, int n_in,
                              void* d_out, int out_size, void* d_ws, size_t ws_size,
                              hipStream_t stream) {
    const float* x       = (const float*)d_in[0];
    const int*   ei      = (const int*)d_in[1];
    const float* W_embed = (const float*)d_in[2];
    const float* b_embed = (const float*)d_in[3];
    const float* W_conv1 = (const float*)d_in[4];
    const float* b_conv1 = (const float*)d_in[5];
    const float* W_conv2 = (const float*)d_in[6];
    const float* b_conv2 = (const float*)d_in[7];
    const float* W_cls   = (const float*)d_in[8];
    const float* b_cls   = (const float*)d_in[9];
    float* out = (float*)d_out;

    char* p = (char*)d_ws;
    size_t o = 0;
    auto carve = [&](size_t bytes) {
        char* r = p + o;
        o = (o + bytes + 255) & ~(size_t)255;
        return r;
    };
    int*      binCnt    = (int*)carve((size_t)BINS * 4);
    int*      binOff    = (int*)carve((size_t)(BINS + 1) * 4);
    int*      binCursor = (int*)carve((size_t)BINS * 4);
    unsigned* arena     = (unsigned*)carve((size_t)Ee * 4);
    int*      rowPtrPad = (int*)carve((size_t)Nn * 4);
    int*      deg       = (int*)carve((size_t)Nn * 4);
    int*      sortedSrc = (int*)carve((size_t)BINS * PADCAP * 4);  // 11.2 MB
    float*    dinv      = (float*)carve((size_t)Nn * 4);
    int*      flag      = (int*)carve(4);
    f16*      WtAll     = (f16*)carve((size_t)3 * D * D * 2);
    f16*      Wct       = (f16*)carve((size_t)CPAD * WS * 2);
    f16*      hcat      = (f16*)carve((size_t)Nn * DCAT * 2);      // 76.8 MB
    f16*      tmpb      = (f16*)carve((size_t)NFB * BLKSTR * 2);   // 25.6 MB blocked
    (void)ws_size;

    hipMemsetAsync(binCnt, 0, (size_t)BINS * 4, stream);
    detect_layout<<<1, 64, 0, stream>>>(ei, flag);
    bin_hist<<<512, 256, 0, stream>>>(ei, flag, binCnt);
    bin_scan<<<1, 512, 0, stream>>>(binCnt, binOff, binCursor);
    bin_scatter<<<NCHUNK, 256, 0, stream>>>(ei, flag, binCursor, arena);
    bin_finalize<<<BINS, 256, 0, stream>>>(binOff, arena, rowPtrPad, deg, dinv, sortedSrc);
    transpose_w<<<3, 256, 0, stream>>>(W_embed, W_conv1, W_conv2, WtAll);
    prep_wcls<<<1, 256, 0, stream>>>(W_cls, Wct, tmpb);

    const int gGemm = (Nn + 127) / 128;
    const int gAggB = (Nn / 4) * NFB;  // 200000 blocks: fb = blockIdx&7 -> XCD affinity

    // h0 = relu(x @ W_embed + b_embed)  -> hcat part 0
    gemm_mfma<1, 0><<<gGemm, 256, 0, stream>>>(x, D, WtAll, b_embed, nullptr, hcat, DCAT, Nn, 1);
    // conv1: tmpb = (h0 @ W1) * dinv (blocked) ; h1 = relu(dinv*(agg+self) + b1) -> hcat part 1
    gemm_mfma<0, 1><<<gGemm, 256, 0, stream>>>(hcat, DCAT, WtAll + D * D, nullptr, dinv, tmpb, 0, Nn, 0);
    aggregate_blk<<<gAggB, 256, 0, stream>>>(tmpb, rowPtrPad, deg, sortedSrc, dinv, b_conv1, hcat, D);
    // conv2 -> hcat part 2
    gemm_mfma<0, 1><<<gGemm, 256, 0, stream>>>(hcat + D, DCAT, WtAll + 2 * D * D, nullptr, dinv, tmpb, 0, Nn, 0);
    aggregate_blk<<<gAggB, 256, 0, stream>>>(tmpb, rowPtrPad, deg, sortedSrc, dinv, b_conv2, hcat, 2 * D);
    // classifier (MFMA over concat)
    cls_mfma<<<gGemm, 256, 0, stream>>>(hcat, Wct, b_cls, out);
}

// Round 7
// 336.170 us; speedup vs baseline: 2.6149x; 2.6149x over previous
//
#include <hip/hip_runtime.h>

// ---------------- problem constants ----------------
constexpr int Nn   = 100000;   // nodes
constexpr int Ee   = 1600000;  // edges
constexpr int D    = 128;      // hidden = input dim
constexpr int DOUT = 40;       // classifier out
constexpr int DCAT = 384;      // 3*D concat width
constexpr int CPAD = 48;       // DOUT padded to 3x16 MFMA col tiles
constexpr int WS   = 392;      // Wct row stride (halfs)

// feature-blocked tmp (conv2 path): 8 blocks x 16 features, 3.2 MB/block -> XCD-L2-resident
constexpr int NFB    = 8;
constexpr int BLKSTR = (Nn + 1) * 16;  // f16 elems per block (+1 sentinel zero row)

// binned-sort parameters
constexpr int BINSH  = 8;                          // 256 nodes per bin
constexpr int BINSZ  = 1 << BINSH;
constexpr int BINS   = (Nn + BINSZ - 1) / BINSZ;   // 391
constexpr int CHUNK  = 8192;                       // edges per scatter block
constexpr int NCHUNK = (Ee + CHUNK - 1) / CHUNK;   // 196
constexpr int SEGCAP = 5376;                       // max edges/bin (mean 4092, +20 sigma)
constexpr int PADCAP = SEGCAP + 7 * BINSZ;         // 7168: per-bin padded arena stride

typedef _Float16 f16;
typedef _Float16 f16x2 __attribute__((ext_vector_type(2)));
typedef _Float16 f16x8 __attribute__((ext_vector_type(8)));
typedef float    f32x4 __attribute__((ext_vector_type(4)));

// ---------------- edge dtype detect (inlined per block; no extra launch) ----------------
// int64 layout => odd 32-bit words are high words == 0. 8 random int32 node ids
// all being 0 has P ~ 1e-40.
__device__ inline int detect_flag(const int* __restrict__ ei) {
    unsigned orv = 0;
#pragma unroll
    for (int j = 1; j < 16; j += 2) orv |= (unsigned)ei[j];
    return orv == 0u;
}

__device__ inline void load_edge(const int* __restrict__ ei, int f, int e, int& s, int& d) {
    if (f) {  // int64: read 8B, use low word
        s = ((const int2*)ei)[e].x;
        d = ((const int2*)ei)[Ee + e].x;
    } else {
        s = ei[e];
        d = ei[Ee + e];
    }
}

// inclusive Hillis-Steele scan of n2 (<=512) ints with 256 threads, double-buffered.
__device__ inline int* scan_incl(int* pa, int* pb, int n2, int tid) {
    for (int off = 1; off < n2; off <<= 1) {
        for (int i = tid; i < n2; i += 256) pb[i] = pa[i] + ((i >= off) ? pa[i - off] : 0);
        __syncthreads();
        int* t = pa; pa = pb; pb = t;
    }
    return pa;
}

// ---------------- P1: per-bin edge histogram ----------------
__global__ __launch_bounds__(256) void bin_hist(const int* __restrict__ ei,
                                                int* __restrict__ binCnt) {
    __shared__ int h[BINS];
    for (int i = threadIdx.x; i < BINS; i += 256) h[i] = 0;
    __syncthreads();
    int f = detect_flag(ei);
    for (int e = blockIdx.x * 256 + threadIdx.x; e < Ee; e += gridDim.x * 256) {
        int s, d;
        load_edge(ei, f, e, s, d);
        if ((unsigned)s < (unsigned)Nn && (unsigned)d < (unsigned)Nn)
            atomicAdd(&h[d >> BINSH], 1);
    }
    __syncthreads();
    for (int i = threadIdx.x; i < BINS; i += 256)
        if (h[i]) atomicAdd(&binCnt[i], h[i]);
}

// ---------------- P2: scan bins -> arena offsets + cursors ----------------
__global__ __launch_bounds__(512) void bin_scan(const int* __restrict__ binCnt,
                                                int* __restrict__ binOff,
                                                int* __restrict__ binCursor) {
    __shared__ int a[512];
    int t = threadIdx.x;
    int v = (t < BINS) ? binCnt[t] : 0;
    a[t] = v;
    __syncthreads();
    for (int off = 1; off < 512; off <<= 1) {
        int x = a[t] + ((t >= off) ? a[t - off] : 0);
        __syncthreads();
        a[t] = x;
        __syncthreads();
    }
    if (t < BINS) { binOff[t] = a[t] - v; binCursor[t] = a[t] - v; }
    if (t == 0) binOff[BINS] = a[BINS - 1];
}

// ---------------- P3: binning scatter (coalesced run writes) ----------------
__global__ __launch_bounds__(256) void bin_scatter(const int* __restrict__ ei,
                                                   int* __restrict__ binCursor,
                                                   unsigned* __restrict__ arena) {
    __shared__ unsigned srec[CHUNK];                       // 32 KB
    __shared__ int bcnt[BINS], bpfx[BINS], bfill[BINS], gbase[BINS];
    __shared__ int pA[512], pB[512];
    const int tid = threadIdx.x;
    const int e0 = blockIdx.x * CHUNK;
    const int n = min(CHUNK, Ee - e0);
    const int f = detect_flag(ei);

    for (int i = tid; i < BINS; i += 256) { bcnt[i] = 0; bfill[i] = 0; }
    __syncthreads();
    for (int i = tid; i < n; i += 256) {
        int s, d;
        load_edge(ei, f, e0 + i, s, d);
        if ((unsigned)s < (unsigned)Nn && (unsigned)d < (unsigned)Nn)
            atomicAdd(&bcnt[d >> BINSH], 1);
    }
    __syncthreads();
    for (int i = tid; i < 512; i += 256) pA[i] = (i < BINS) ? bcnt[i] : 0;
    __syncthreads();
    int* incl = scan_incl(pA, pB, 512, tid);
    for (int i = tid; i < BINS; i += 256) {
        bpfx[i] = incl[i] - bcnt[i];
        gbase[i] = bcnt[i] ? atomicAdd(&binCursor[i], bcnt[i]) : 0;
    }
    __syncthreads();
    for (int i = tid; i < n; i += 256) {
        int s, d;
        load_edge(ei, f, e0 + i, s, d);
        if ((unsigned)s < (unsigned)Nn && (unsigned)d < (unsigned)Nn) {
            int bin = d >> BINSH;
            int lp = atomicAdd(&bfill[bin], 1);
            srec[bpfx[bin] + lp] = ((unsigned)(d & (BINSZ - 1)) << 17) | (unsigned)s;
        }
    }
    __syncthreads();
    const int wid = tid >> 6, lane = tid & 63;
    for (int bin = wid; bin < BINS; bin += 4) {
        int cnt = bcnt[bin], off = bpfx[bin], gb = gbase[bin];
        for (int j = lane; j < cnt; j += 64) arena[gb + j] = srec[off + j];
    }
}

// ---------------- P4: per-bin finalize -> PADDED CSR (+deg, dinv) ----------------
__global__ __launch_bounds__(256) void bin_finalize(const int* __restrict__ binOff,
                                                    const unsigned* __restrict__ arena,
                                                    int* __restrict__ rowPtrPad,
                                                    int* __restrict__ deg,
                                                    float* __restrict__ dinv,
                                                    int* __restrict__ sortedSrc) {
    __shared__ unsigned seg[SEGCAP];   // 21 KB
    __shared__ int ssrc[PADCAP];       // 28.7 KB
    __shared__ int cnt[BINSZ], fill[BINSZ], pA[BINSZ], pB[BINSZ];
    const int tid = threadIdx.x;
    const int b = blockIdx.x;
    const int base = binOff[b];
    int len = binOff[b + 1] - base;
    if (len > SEGCAP) len = SEGCAP;

    for (int i = tid; i < len; i += 256) seg[i] = arena[base + i];
    for (int i = tid; i < BINSZ; i += 256) { cnt[i] = 0; fill[i] = 0; }
    __syncthreads();
    for (int i = tid; i < len; i += 256) atomicAdd(&cnt[seg[i] >> 17], 1);
    __syncthreads();
    for (int i = tid; i < BINSZ; i += 256) pA[i] = (cnt[i] + 7) & ~7;  // padded counts
    __syncthreads();
    int* incl = scan_incl(pA, pB, BINSZ, tid);

    const int node0 = b * BINSZ;
    const int padLen = incl[BINSZ - 1];
    for (int t = tid; t < BINSZ; t += 256) {
        int node = node0 + t;
        if (node < Nn) {
            int pc = (cnt[t] + 7) & ~7;
            rowPtrPad[node] = b * PADCAP + incl[t] - pc;
            deg[node] = cnt[t];
            dinv[node] = rsqrtf((float)(cnt[t] + 1));  // +1 self loop
        }
    }
    for (int i = tid; i < padLen; i += 256) ssrc[i] = Nn;  // sentinel -> zero row
    __syncthreads();
    for (int i = tid; i < len; i += 256) {
        unsigned r = seg[i];
        int dl = r >> 17, s = (int)(r & 0x1FFFFu);
        int pc = (cnt[dl] + 7) & ~7;
        int p = atomicAdd(&fill[dl], 1);
        ssrc[incl[dl] - pc + p] = s;
    }
    __syncthreads();
    for (int i = tid; i < padLen; i += 256) sortedSrc[(size_t)b * PADCAP + i] = ssrc[i];
}

// ---------------- merged prep: conv-W transposes (blocks 0-2), Wct + tmp sentinel (block 3) ----
__global__ __launch_bounds__(256) void prep_all(const float* __restrict__ W0,
                                                const float* __restrict__ W1,
                                                const float* __restrict__ W2,
                                                const float* __restrict__ Wc,
                                                f16* __restrict__ WtAll,
                                                f16* __restrict__ Wct,
                                                f16* __restrict__ tmp) {
    int b = blockIdx.x;
    if (b < 3) {
        const float* W = (b == 0) ? W0 : ((b == 1) ? W1 : W2);
        f16* Wt = WtAll + (size_t)b * D * D;
        for (int i = threadIdx.x; i < D * D; i += 256) {
            int k = i >> 7, c = i & 127;
            Wt[c * D + k] = (f16)W[i];
        }
    } else {
        if (threadIdx.x < D) tmp[(size_t)Nn * D + threadIdx.x] = (f16)0.0f;  // row-major sentinel
        for (int i = threadIdx.x; i < CPAD * WS; i += 256) {
            int c = i / WS, k = i - c * WS;
            f16 v = (f16)0.0f;
            if (c < DOUT && k < DCAT) v = (f16)Wc[k * DOUT + c];
            Wct[i] = v;
        }
    }
}

// tmpb aliases tmp: re-zero the 8 per-block sentinel rows after aggregate_pad is done.
__global__ void zero_sent2(f16* __restrict__ tmpb) {
    if (threadIdx.x < NFB * 16) {
        int fb = threadIdx.x >> 4, j = threadIdx.x & 15;
        tmpb[(size_t)fb * BLKSTR + (size_t)Nn * 16 + j] = (f16)0.0f;
    }
}

// ---------------- fused embed+conv1 GEMM ----------------
// h0 = relu(x @ We^T + b_e): written to hcat part0 AND kept in LDS (swizzled);
// tmp = (h0 @ W1^T) * dinv: row-major. Saves the 25.6 MB h0 re-read.
__global__ __launch_bounds__(256) void gemm_fused01(const float* __restrict__ x,
                                                    const f16* __restrict__ WeT,
                                                    const f16* __restrict__ W1T,
                                                    const float* __restrict__ b_embed,
                                                    const float* __restrict__ dinv,
                                                    f16* __restrict__ hcat,
                                                    f16* __restrict__ tmp) {
    __shared__ f16 Bsw[128 * 128];  // 32 KB (We^T, then W1^T)
    __shared__ f16 Hsw[128 * 128];  // 32 KB h0 tile
    const int tid = threadIdx.x;
    const int r0 = blockIdx.x * 128;
    const int lane = tid & 63;
    const int w = tid >> 6;
    const int wr = w * 32;

    {   // stage We^T
        int row = tid >> 1, half = (tid & 1) * 128;
#pragma unroll
        for (int i = 0; i < 8; ++i) {
            int bir = half + i * 16;
            uint4 v = *(const uint4*)((const char*)WeT + (size_t)row * 256 + bir);
            *(uint4*)((char*)Bsw + row * 256 + (bir ^ ((row & 7) << 4))) = v;
        }
    }
    __syncthreads();

    f32x4 acc[2][8];
#pragma unroll
    for (int mf = 0; mf < 2; ++mf)
#pragma unroll
        for (int nf = 0; nf < 8; ++nf) acc[mf][nf] = (f32x4){0, 0, 0, 0};

    // ---- GEMM0: A = x (fp32, direct from global) ----
#pragma unroll
    for (int kk = 0; kk < 4; ++kk) {
        const int ke = kk * 32 + (lane >> 4) * 8;
        f16x8 a[2], b[8];
#pragma unroll
        for (int mf = 0; mf < 2; ++mf) {
            int row = r0 + wr + mf * 16 + (lane & 15);
            int rc = (row < Nn) ? row : (Nn - 1);
            const float* p = x + (size_t)rc * D + ke;
            float4 f0 = *(const float4*)p;
            float4 f1 = *(const float4*)(p + 4);
            f16x8 h;
            h[0] = (f16)f0.x; h[1] = (f16)f0.y; h[2] = (f16)f0.z; h[3] = (f16)f0.w;
            h[4] = (f16)f1.x; h[5] = (f16)f1.y; h[6] = (f16)f1.z; h[7] = (f16)f1.w;
            a[mf] = h;
        }
#pragma unroll
        for (int nf = 0; nf < 8; ++nf) {
            int col = nf * 16 + (lane & 15);
            int bir = kk * 64 + (lane >> 4) * 16;
            b[nf] = *(const f16x8*)((const char*)Bsw + col * 256 + (bir ^ ((col & 7) << 4)));
        }
#pragma unroll
        for (int mf = 0; mf < 2; ++mf)
#pragma unroll
            for (int nf = 0; nf < 8; ++nf)
                acc[mf][nf] = __builtin_amdgcn_mfma_f32_16x16x32_f16(a[mf], b[nf], acc[mf][nf], 0, 0, 0);
    }

    // ---- epilogue0: bias+relu -> hcat part0 + Hsw (swizzled) ----
    {
        float bv[8];
#pragma unroll
        for (int nf = 0; nf < 8; ++nf) bv[nf] = b_embed[nf * 16 + (lane & 15)];
#pragma unroll
        for (int mf = 0; mf < 2; ++mf) {
#pragma unroll
            for (int i = 0; i < 4; ++i) {
                int lrow = wr + mf * 16 + (lane >> 4) * 4 + i;
                int row = r0 + lrow;
#pragma unroll
                for (int nf = 0; nf < 8; ++nf) {
                    float v = acc[mf][nf][i] + bv[nf];
                    if (v < 0.0f) v = 0.0f;
                    f16 hv = (f16)v;
                    if (row < Nn) hcat[(size_t)row * DCAT + nf * 16 + (lane & 15)] = hv;
                    int bir = (nf * 16 + (lane & 15)) * 2;
                    *(f16*)((char*)Hsw + lrow * 256 + (bir ^ ((lrow & 7) << 4))) = hv;
                }
            }
        }
    }
    __syncthreads();

    {   // restage W1^T
        int row = tid >> 1, half = (tid & 1) * 128;
#pragma unroll
        for (int i = 0; i < 8; ++i) {
            int bir = half + i * 16;
            uint4 v = *(const uint4*)((const char*)W1T + (size_t)row * 256 + bir);
            *(uint4*)((char*)Bsw + row * 256 + (bir ^ ((row & 7) << 4))) = v;
        }
    }
#pragma unroll
    for (int mf = 0; mf < 2; ++mf)
#pragma unroll
        for (int nf = 0; nf < 8; ++nf) acc[mf][nf] = (f32x4){0, 0, 0, 0};
    __syncthreads();

    // ---- GEMM1: A = h0 tile from Hsw ----
#pragma unroll
    for (int kk = 0; kk < 4; ++kk) {
        f16x8 a[2], b[8];
#pragma unroll
        for (int mf = 0; mf < 2; ++mf) {
            int lrow = wr + mf * 16 + (lane & 15);
            int bir = kk * 64 + (lane >> 4) * 16;
            a[mf] = *(const f16x8*)((const char*)Hsw + lrow * 256 + (bir ^ ((lrow & 7) << 4)));
        }
#pragma unroll
        for (int nf = 0; nf < 8; ++nf) {
            int col = nf * 16 + (lane & 15);
            int bir = kk * 64 + (lane >> 4) * 16;
            b[nf] = *(const f16x8*)((const char*)Bsw + col * 256 + (bir ^ ((col & 7) << 4)));
        }
#pragma unroll
        for (int mf = 0; mf < 2; ++mf)
#pragma unroll
            for (int nf = 0; nf < 8; ++nf)
                acc[mf][nf] = __builtin_amdgcn_mfma_f32_16x16x32_f16(a[mf], b[nf], acc[mf][nf], 0, 0, 0);
    }

    // ---- epilogue1: tmp = acc * dinv (row-major) ----
#pragma unroll
    for (int mf = 0; mf < 2; ++mf) {
#pragma unroll
        for (int i = 0; i < 4; ++i) {
            int row = r0 + wr + mf * 16 + (lane >> 4) * 4 + i;
            if (row < Nn) {
                float sc = dinv[row];
#pragma unroll
                for (int nf = 0; nf < 8; ++nf)
                    tmp[(size_t)row * D + nf * 16 + (lane & 15)] = (f16)(acc[mf][nf][i] * sc);
            }
        }
    }
}

// ---------------- MFMA GEMM (conv2): C = (A @ Wt^T) * scale ----------------
// BLOCKED=1 epilogue writes feature-blocked C[fb][row][16].
template <int BLOCKED>
__global__ __launch_bounds__(256) void gemm_mfma(const f16* __restrict__ Ain, int sA,
                                                 const f16* __restrict__ Wt,
                                                 const float* __restrict__ scale,
                                                 f16* __restrict__ C,
                                                 int M) {
    __shared__ f16 Bsw[128 * 128];  // 32 KB
    const int tid = threadIdx.x;
    const int r0 = blockIdx.x * 128;

    {   // stage B
        int row = tid >> 1, half = (tid & 1) * 128;
#pragma unroll
        for (int i = 0; i < 8; ++i) {
            int bir = half + i * 16;
            uint4 v = *(const uint4*)((const char*)Wt + (size_t)row * 256 + bir);
            *(uint4*)((char*)Bsw + row * 256 + (bir ^ ((row & 7) << 4))) = v;
        }
    }
    __syncthreads();

    const int lane = tid & 63;
    const int w    = tid >> 6;
    const int wr   = w * 32;

    f32x4 acc[2][8];
#pragma unroll
    for (int mf = 0; mf < 2; ++mf)
#pragma unroll
        for (int nf = 0; nf < 8; ++nf) acc[mf][nf] = (f32x4){0, 0, 0, 0};

#pragma unroll
    for (int kk = 0; kk < 4; ++kk) {
        const int ke = kk * 32 + (lane >> 4) * 8;
        f16x8 a[2], b[8];
#pragma unroll
        for (int mf = 0; mf < 2; ++mf) {
            int row = r0 + wr + mf * 16 + (lane & 15);
            int rc = (row < M) ? row : (M - 1);
            a[mf] = *(const f16x8*)(Ain + (size_t)rc * sA + ke);
        }
#pragma unroll
        for (int nf = 0; nf < 8; ++nf) {
            int col = nf * 16 + (lane & 15);
            int bir = kk * 64 + (lane >> 4) * 16;
            b[nf] = *(const f16x8*)((const char*)Bsw + col * 256 + (bir ^ ((col & 7) << 4)));
        }
#pragma unroll
        for (int mf = 0; mf < 2; ++mf)
#pragma unroll
            for (int nf = 0; nf < 8; ++nf)
                acc[mf][nf] = __builtin_amdgcn_mfma_f32_16x16x32_f16(a[mf], b[nf], acc[mf][nf], 0, 0, 0);
    }

#pragma unroll
    for (int mf = 0; mf < 2; ++mf) {
#pragma unroll
        for (int i = 0; i < 4; ++i) {
            int row = r0 + wr + mf * 16 + (lane >> 4) * 4 + i;
            if (row < M) {
                float sc = scale[row];
#pragma unroll
                for (int nf = 0; nf < 8; ++nf) {
                    float v = acc[mf][nf][i] * sc;
                    if (BLOCKED)
                        C[(size_t)nf * BLKSTR + (size_t)row * 16 + (lane & 15)] = (f16)v;
                    else
                        C[(size_t)row * D + nf * 16 + (lane & 15)] = (f16)v;
                }
            }
        }
    }
}

// ---------------- conv1 aggregation: row-major tmp, 8-deep gather (known 63 us) ----------------
__global__ __launch_bounds__(256) void aggregate_pad(const f16* __restrict__ tmp,
                                                     const int* __restrict__ rowPtrPad,
                                                     const int* __restrict__ deg,
                                                     const int* __restrict__ sortedSrc,
                                                     const float* __restrict__ dinv,
                                                     const float* __restrict__ bias,
                                                     f16* __restrict__ hcat, int partOff) {
    int node = (blockIdx.x * 256 + threadIdx.x) >> 6;  // one wave per node
    int lane = threadIdx.x & 63;
    if (node >= Nn) return;
    const f16x2* t2 = (const f16x2*)tmp;

    int base = rowPtrPad[node];
    int pc = (deg[node] + 7) & ~7;
    float di = dinv[node];

    f16x2 sv = t2[(size_t)node * 64 + lane];  // self (already *dinv[node])
    float ax = (float)sv[0];
    float ay = (float)sv[1];

    for (int e = 0; e < pc; e += 8) {
        int4 ia = *(const int4*)(sortedSrc + base + e);
        int4 ib = *(const int4*)(sortedSrc + base + e + 4);
        f16x2 g0 = t2[(size_t)ia.x * 64 + lane];
        f16x2 g1 = t2[(size_t)ia.y * 64 + lane];
        f16x2 g2 = t2[(size_t)ia.z * 64 + lane];
        f16x2 g3 = t2[(size_t)ia.w * 64 + lane];
        f16x2 g4 = t2[(size_t)ib.x * 64 + lane];
        f16x2 g5 = t2[(size_t)ib.y * 64 + lane];
        f16x2 g6 = t2[(size_t)ib.z * 64 + lane];
        f16x2 g7 = t2[(size_t)ib.w * 64 + lane];
        f16x2 s0 = g0 + g1, s1 = g2 + g3, s2 = g4 + g5, s3 = g6 + g7;
        f16x2 s4 = s0 + s1, s5 = s2 + s3;
        ax += (float)s4[0] + (float)s5[0];
        ay += (float)s4[1] + (float)s5[1];
    }

    float2 bb = ((const float2*)bias)[lane];
    ax = di * ax + bb.x;
    ay = di * ay + bb.y;
    if (ax < 0.0f) ax = 0.0f;
    if (ay < 0.0f) ay = 0.0f;
    f16x2 o;
    o[0] = (f16)ax;
    o[1] = (f16)ay;
    *(f16x2*)(hcat + (size_t)node * DCAT + partOff + lane * 2) = o;
}

// ---------------- conv2 aggregation: fb-blocked + XCD affinity, 8 nodes/wave ----------------
// lane = (node lane>>3) x (feature-pair lane&7). 8 independent gather chains per wave,
// index prefetch pipelined. No cross-lane reduce (edge loop IS the reduction).
__global__ __launch_bounds__(256) void aggregate_blk2(const f16* __restrict__ tmpb,
                                                      const int* __restrict__ rowPtrPad,
                                                      const int* __restrict__ deg,
                                                      const int* __restrict__ sortedSrc,
                                                      const float* __restrict__ dinv,
                                                      const float* __restrict__ bias,
                                                      f16* __restrict__ hcat, int partOff) {
    const int fb   = blockIdx.x & 7;                 // -> XCD affinity (round-robin)
    const int wid  = threadIdx.x >> 6;
    const int lane = threadIdx.x & 63;
    const int n    = (blockIdx.x >> 3) * 32 + (wid << 3) + (lane >> 3);  // Nn % 32 == 0
    const int f    = lane & 7;
    const f16x2* tb = (const f16x2*)(tmpb + (size_t)fb * BLKSTR);

    const int base = rowPtrPad[n];   // 8 lanes/group same addr -> broadcast
    const int pc   = (deg[n] + 7) & ~7;
    const float di = dinv[n];

    f16x2 sv = tb[(size_t)n * 8 + f];  // self (already *dinv[n])
    float ax = (float)sv[0];
    float ay = (float)sv[1];

    int e = 0;
    int s0 = (0 < pc) ? sortedSrc[base] : Nn;
    int s1 = (1 < pc) ? sortedSrc[base + 1] : Nn;
    while (__any(e < pc)) {
        int t0 = (e + 2 < pc) ? sortedSrc[base + e + 2] : Nn;  // prefetch next pair
        int t1 = (e + 3 < pc) ? sortedSrc[base + e + 3] : Nn;
        f16x2 g0 = tb[(size_t)s0 * 8 + f];  // L2-resident (3.2 MB block)
        f16x2 g1 = tb[(size_t)s1 * 8 + f];
        ax += (float)g0[0] + (float)g1[0];
        ay += (float)g0[1] + (float)g1[1];
        s0 = t0; s1 = t1; e += 2;
    }

    float2 bb = *(const float2*)(bias + fb * 16 + f * 2);
    float ox = di * ax + bb.x;
    float oy = di * ay + bb.y;
    if (ox < 0.0f) ox = 0.0f;
    if (oy < 0.0f) oy = 0.0f;
    f16x2 o;
    o[0] = (f16)ox;
    o[1] = (f16)oy;
    *(f16x2*)(hcat + (size_t)n * DCAT + partOff + fb * 16 + f * 2) = o;
}

// ---------------- MFMA classifier: out[N,40] = hcat[N,384] @ Wct^T + b ----------------
__global__ __launch_bounds__(256) void cls_mfma(const f16* __restrict__ hcat,
                                                const f16* __restrict__ Wct,
                                                const float* __restrict__ bc,
                                                float* __restrict__ out) {
    __shared__ f16 Bs[CPAD * WS];  // 37.6 KB
    const int tid = threadIdx.x;
    for (int i = tid; i < CPAD * WS / 8; i += 256)
        ((uint4*)Bs)[i] = ((const uint4*)Wct)[i];
    __syncthreads();

    const int lane = tid & 63;
    const int w    = tid >> 6;
    const int r0   = blockIdx.x * 128 + w * 32;

    f32x4 acc[2][3];
#pragma unroll
    for (int mf = 0; mf < 2; ++mf)
#pragma unroll
        for (int nf = 0; nf < 3; ++nf) acc[mf][nf] = (f32x4){0, 0, 0, 0};

#pragma unroll 3
    for (int kk = 0; kk < 12; ++kk) {
        const int ke = kk * 32 + (lane >> 4) * 8;
        f16x8 a[2], b[3];
#pragma unroll
        for (int mf = 0; mf < 2; ++mf) {
            int row = r0 + mf * 16 + (lane & 15);
            int rc = (row < Nn) ? row : (Nn - 1);
            a[mf] = *(const f16x8*)(hcat + (size_t)rc * DCAT + ke);
        }
#pragma unroll
        for (int nf = 0; nf < 3; ++nf) {
            int col = nf * 16 + (lane & 15);
            b[nf] = *(const f16x8*)(Bs + col * WS + ke);
        }
#pragma unroll
        for (int mf = 0; mf < 2; ++mf)
#pragma unroll
            for (int nf = 0; nf < 3; ++nf)
                acc[mf][nf] = __builtin_amdgcn_mfma_f32_16x16x32_f16(a[mf], b[nf], acc[mf][nf], 0, 0, 0);
    }

    float bv[3];
#pragma unroll
    for (int nf = 0; nf < 3; ++nf) {
        int col = nf * 16 + (lane & 15);
        bv[nf] = (col < DOUT) ? bc[col] : 0.0f;
    }
#pragma unroll
    for (int mf = 0; mf < 2; ++mf) {
#pragma unroll
        for (int i = 0; i < 4; ++i) {
            int row = r0 + mf * 16 + (lane >> 4) * 4 + i;
            if (row < Nn) {
#pragma unroll
                for (int nf = 0; nf < 3; ++nf) {
                    int col = nf * 16 + (lane & 15);
                    if (col < DOUT) out[(size_t)row * DOUT + col] = acc[mf][nf][i] + bv[nf];
                }
            }
        }
    }
}

// ---------------- launch ----------------
extern "C" void kernel_launch(void* const* d_in, const int* in_sizes, int n_in,
                              void* d_out, int out_size, void* d_ws, size_t ws_size,
                              hipStream_t stream) {
    const float* x       = (const float*)d_in[0];
    const int*   ei      = (const int*)d_in[1];
    const float* W_embed = (const float*)d_in[2];
    const float* b_embed = (const float*)d_in[3];
    const float* W_conv1 = (const float*)d_in[4];
    const float* b_conv1 = (const float*)d_in[5];
    const float* W_conv2 = (const float*)d_in[6];
    const float* b_conv2 = (const float*)d_in[7];
    const float* W_cls   = (const float*)d_in[8];
    const float* b_cls   = (const float*)d_in[9];
    float* out = (float*)d_out;

    char* p = (char*)d_ws;
    size_t o = 0;
    auto carve = [&](size_t bytes) {
        char* r = p + o;
        o = (o + bytes + 255) & ~(size_t)255;
        return r;
    };
    int*      binCnt    = (int*)carve((size_t)BINS * 4);
    int*      binOff    = (int*)carve((size_t)(BINS + 1) * 4);
    int*      binCursor = (int*)carve((size_t)BINS * 4);
    int*      rowPtrPad = (int*)carve((size_t)Nn * 4);
    int*      deg       = (int*)carve((size_t)Nn * 4);
    int*      sortedSrc = (int*)carve(((size_t)BINS * PADCAP + 1024) * 4);  // 11.2 MB
    float*    dinv      = (float*)carve((size_t)Nn * 4);
    f16*      WtAll     = (f16*)carve((size_t)3 * D * D * 2);
    f16*      Wct       = (f16*)carve((size_t)CPAD * WS * 2);
    f16*      hcat      = (f16*)carve((size_t)Nn * DCAT * 2);      // 76.8 MB
    f16*      tmp       = (f16*)carve((size_t)(Nn + 1) * D * 2);   // 25.6 MB (+sentinel row)
    (void)ws_size;

    // liveness aliases: arena (sort-only) overlays hcat; tmpb (conv2) overlays tmp (conv1)
    unsigned* arena = (unsigned*)hcat;   // 6.4 MB, dead before first hcat write
    f16*      tmpb  = tmp;               // same size; sentinels re-zeroed by zero_sent2

    hipMemsetAsync(binCnt, 0, (size_t)BINS * 4, stream);
    bin_hist<<<512, 256, 0, stream>>>(ei, binCnt);
    bin_scan<<<1, 512, 0, stream>>>(binCnt, binOff, binCursor);
    bin_scatter<<<NCHUNK, 256, 0, stream>>>(ei, binCursor, arena);
    bin_finalize<<<BINS, 256, 0, stream>>>(binOff, arena, rowPtrPad, deg, dinv, sortedSrc);
    prep_all<<<4, 256, 0, stream>>>(W_embed, W_conv1, W_conv2, W_cls, WtAll, Wct, tmp);

    const int gGemm = (Nn + 127) / 128;
    const int gAgg  = (Nn * 64) / 256;
    const int gAgg2 = (Nn / 32) * NFB;  // 25000, fb = blockIdx&7

    // embed + conv1-GEMM fused: hcat part0 + tmp
    gemm_fused01<<<gGemm, 256, 0, stream>>>(x, WtAll, WtAll + D * D, b_embed, dinv, hcat, tmp);
    // conv1 aggregate -> hcat part1
    aggregate_pad<<<gAgg, 256, 0, stream>>>(tmp, rowPtrPad, deg, sortedSrc, dinv, b_conv1, hcat, D);
    zero_sent2<<<1, 256, 0, stream>>>(tmpb);
    // conv2: tmpb = (h1 @ W2)*dinv (blocked), then fb-affine aggregate -> hcat part2
    gemm_mfma<1><<<gGemm, 256, 0, stream>>>(hcat + D, DCAT, WtAll + 2 * D * D, dinv, tmpb, Nn);
    aggregate_blk2<<<gAgg2, 256, 0, stream>>>(tmpb, rowPtrPad, deg, sortedSrc, dinv, b_conv2, hcat, 2 * D);
    // classifier
    cls_mfma<<<gGemm, 256, 0, stream>>>(hcat, Wct, b_cls, out);
}